// Round 9
// baseline (299.715 us; speedup 1.0000x reference)
//
#include <hip/hip_runtime.h>
#include <hip/hip_bf16.h>

#define T_LEN 2048
#define D_DIM 1024
#define H_NUM 16
#define DK 64

typedef unsigned short u16;
typedef __bf16 bf16x8 __attribute__((ext_vector_type(8)));
typedef float f32x4 __attribute__((ext_vector_type(4)));
typedef u16 u16x8 __attribute__((ext_vector_type(8)));
typedef u16 u16x4 __attribute__((ext_vector_type(4)));

#define AS1 __attribute__((address_space(1)))
#define AS3 __attribute__((address_space(3)))

// Q pre-scale: 1/sqrt(64) * log2(e)  (softmax done in exp2 domain)
#define QSCALE 0.18033688011112042f

__device__ __forceinline__ u16 f2bf(float f) {
    unsigned u = __builtin_bit_cast(unsigned, f);
    unsigned rounding = 0x7FFFu + ((u >> 16) & 1u);
    return (u16)((u + rounding) >> 16);
}

// ---------------- f32 -> bf16 conversion (8 elems / thread) ----------------
__global__ __launch_bounds__(256) void cvt_bf16(const float* __restrict__ in,
                                                u16* __restrict__ out, int n8) {
    int i = blockIdx.x * blockDim.x + threadIdx.x;
    if (i >= n8) return;
    const float4* p = (const float4*)in + (size_t)i * 2;
    float4 a = p[0], b = p[1];
    u16x8 r;
    r[0] = f2bf(a.x); r[1] = f2bf(a.y); r[2] = f2bf(a.z); r[3] = f2bf(a.w);
    r[4] = f2bf(b.x); r[5] = f2bf(b.y); r[6] = f2bf(b.z); r[7] = f2bf(b.w);
    *((u16x8*)out + i) = r;
}

__global__ __launch_bounds__(256) void cvt4_bf16(const float* __restrict__ a,
                                                 const float* __restrict__ b,
                                                 const float* __restrict__ c,
                                                 const float* __restrict__ d,
                                                 u16* __restrict__ out, int n8per) {
    int s = blockIdx.y;
    const float* src = s == 0 ? a : (s == 1 ? b : (s == 2 ? c : d));
    int i = blockIdx.x * blockDim.x + threadIdx.x;
    if (i >= n8per) return;
    const float4* p = (const float4*)src + (size_t)i * 2;
    float4 x = p[0], y = p[1];
    u16x8 r;
    r[0] = f2bf(x.x); r[1] = f2bf(x.y); r[2] = f2bf(x.z); r[3] = f2bf(x.w);
    r[4] = f2bf(y.x); r[5] = f2bf(y.y); r[6] = f2bf(y.z); r[7] = f2bf(y.w);
    *((u16x8*)(out + (size_t)s * n8per * 8) + i) = r;
}

// ======= GEMM: BM=128 x BN=256, BK=64 (2 kk-halves), 8 waves, pipelined =====
// C[M=8192, N=NYT*256] = A[M,1024] * W[N,1024]^T + bias.
// LDS: LA[2 par][2 kk][128x32] (8KB each) + LB[2][2][256x32] (16KB) = 96 KB.
// Per K-tile: 2 phases (kk=0,1), 16 MFMA each. Stage slots: p0 issues
// kk1(t+1) [3 loads], p1 issues kk0(t+2) [3 loads]; every slot's region had
// its last reader pass the previous barrier. Counted vmcnt ledger (derived):
// steady 9; tails p0:3 (t=NT-1), p1:6 (t=NT-2), 0 (t=NT-1).
// Swizzle both sides: store chunk' = chunk ^ ((row>>1)&3); read gsw.
// MODE 0: f32 row-major (final proj, N=1024). MODE 1: bf16 [mtx][B,H,T,DK].
template <int MODE, int NYT>
__global__ __launch_bounds__(512) void gemm_bp(const u16* __restrict__ A,
                                               const u16* __restrict__ W,
                                               const float* __restrict__ b0,
                                               const float* __restrict__ b1,
                                               const float* __restrict__ b2,
                                               void* __restrict__ Cout) {
    __shared__ u16 LA[2][2][4096];
    __shared__ u16 LB[2][2][8192];
    const int tid = threadIdx.x, w = tid >> 6, lane = tid & 63;
    const int loc = blockIdx.x >> 3;
    const int xm = (blockIdx.x & 7) * 8 + loc / NYT;   // 8 m-panels per XCD
    const int yn = loc % NYT;
    const int tm = xm * 128, tn = yn * 256;
    const int wr = w >> 2, wc = w & 3;
    const int wm = wr * 64, wn = wc * 64;
    const int g = lane >> 4, ccol = lane & 15;
    const int gsw = (g ^ ((ccol >> 1) & 3)) * 8;       // read-side swizzle
    const int NT = 16;                                  // K=1024 / BK=64

    const int srow = tid >> 2;
    const int skk = ((tid & 3) ^ ((tid >> 3) & 3)) * 8; // inverse swizzle

    f32x4 acc[4][4] = {};

    auto stageA = [&](int par, int kk, int k0) {
        __builtin_amdgcn_global_load_lds(
            (AS1 const void*)(A + (size_t)(tm + srow) * 1024 + k0 + kk * 32 + skk),
            (AS3 void*)(&LA[par][kk][w * 512]), 16, 0, 0);
    };
    auto stageB = [&](int par, int kk, int k0) {
#pragma unroll
        for (int h = 0; h < 2; ++h)
            __builtin_amdgcn_global_load_lds(
                (AS1 const void*)(W + (size_t)(tn + h * 128 + srow) * 1024 + k0 + kk * 32 + skk),
                (AS3 void*)(&LB[par][kk][h * 4096 + w * 512]), 16, 0, 0);
    };

    // prologue: kk0(t0), kk1(t0), kk0(t1)  (9 loads, oldest-first order)
    stageA(0, 0, 0);  stageB(0, 0, 0);
    stageA(0, 1, 0);  stageB(0, 1, 0);
    stageA(1, 0, 64); stageB(1, 0, 64);

    for (int t = 0; t < NT; ++t) {
        const int par = t & 1;
#pragma unroll
        for (int ph = 0; ph < 2; ++ph) {
            // stage into the slot whose readers all passed the last barrier
            if (ph == 0) {
                if (t + 1 < NT) { stageA(par ^ 1, 1, (t + 1) * 64); stageB(par ^ 1, 1, (t + 1) * 64); }
            } else {
                if (t + 2 < NT) { stageA(par, 0, (t + 2) * 64); stageB(par, 0, (t + 2) * 64); }
            }
            // counted vmcnt ledger
            if (ph == 0) {
                if (t < NT - 1) asm volatile("s_waitcnt vmcnt(9)" ::: "memory");
                else            asm volatile("s_waitcnt vmcnt(3)" ::: "memory");
            } else {
                if (t < NT - 2)      asm volatile("s_waitcnt vmcnt(9)" ::: "memory");
                else if (t == NT - 2) asm volatile("s_waitcnt vmcnt(6)" ::: "memory");
                else                 asm volatile("s_waitcnt vmcnt(0)" ::: "memory");
            }
            __builtin_amdgcn_s_barrier();

            const u16* LAp = LA[par][ph];
            const u16* LBp = LB[par][ph];
            bf16x8 af[4], bfr[4];
#pragma unroll
            for (int i = 0; i < 4; ++i) {
                af[i]  = *(const bf16x8*)(LAp + (wm + i * 16 + ccol) * 32 + gsw);
                bfr[i] = *(const bf16x8*)(LBp + (wn + i * 16 + ccol) * 32 + gsw);
            }
            asm volatile("s_waitcnt lgkmcnt(0)" ::: "memory");
            __builtin_amdgcn_sched_barrier(0);
            __builtin_amdgcn_s_setprio(1);
#pragma unroll
            for (int mi = 0; mi < 4; ++mi)
#pragma unroll
                for (int ni = 0; ni < 4; ++ni)
                    acc[mi][ni] = __builtin_amdgcn_mfma_f32_16x16x32_bf16(
                        af[mi], bfr[ni], acc[mi][ni], 0, 0, 0);
            __builtin_amdgcn_s_setprio(0);
            __builtin_amdgcn_s_barrier();
        }
    }

    // epilogue
    const int mtx = yn >> 2;
    const float* bp = MODE == 0 ? b0 : (mtx == 0 ? b0 : (mtx == 1 ? b1 : b2));
#pragma unroll
    for (int mi = 0; mi < 4; ++mi) {
#pragma unroll
        for (int ni = 0; ni < 4; ++ni) {
            int n = tn + wn + ni * 16 + ccol;
            float bv = bp[n & 1023];
#pragma unroll
            for (int r = 0; r < 4; ++r) {
                int m = tm + wm + mi * 16 + g * 4 + r;
                float val = acc[mi][ni][r] + bv;
                if (MODE == 0) {
                    ((float*)Cout)[(size_t)m * 1024 + n] = val;
                } else {
                    if (mtx == 0) val *= QSCALE;
                    int nn = n & 1023;
                    int h = nn >> 6, d = nn & 63;
                    int b = m >> 11, tt = m & (T_LEN - 1);
                    ((u16*)Cout)[(size_t)mtx * 8388608 +
                                 ((size_t)(b * H_NUM + h) * T_LEN + tt) * DK + d] = f2bf(val);
                }
            }
        }
    }
}

// ---------------- Flash attention, causal ----------------
// grid 512 (XCD-decoded), block 512 (8 waves). Block handles q-block pair
// {bx, 15-bx} of 128 rows; wave w owns 16 rows. KV tile 64, double-buffered.
// SWAPPED QK^T: S^T = mfma(K, Q) -> each lane holds 16 S-values for ONE q.
__global__ __launch_bounds__(512) void attn_fwd(const u16* __restrict__ q,
                                                const u16* __restrict__ k,
                                                const u16* __restrict__ v,
                                                u16* __restrict__ o) {
    __shared__ u16 lK[2][64 * 64];     // [key][d], 16B-window ^= key&7
    __shared__ u16 lV[2][64 * 64];     // [d][key], 16B-window ^= (d>>1)&7
    __shared__ u16 lP[8][16 * 72];     // per-wave P, row stride 144B
    __shared__ float lSc[8][16];       // softmax-layout -> C-layout relay

    const int tid = threadIdx.x, w = tid >> 6, lane = tid & 63;
    const int bid = blockIdx.x;
    const int idx = bid >> 3;
    const int bh = (bid & 7) * 8 + (idx & 7);    // 8 bh per XCD
    const int bx = idx >> 3;

    const u16* qb = q + (size_t)bh * T_LEN * DK;
    const u16* kb = k + (size_t)bh * T_LEN * DK;
    const u16* vb = v + (size_t)bh * T_LEN * DK;

    const int g = lane >> 4;
    const int ccol = lane & 15;
    const int kg = tid >> 4;
    const int dc = tid & 15;
    const int wk = w - 4;
    const int b_ = bh >> 4, h_ = bh & 15;

    for (int seg = 0; seg < 2; ++seg) {
        const int qblk = seg ? (15 - bx) : bx;
        const int q0 = qblk * 128;
        const int ntiles = 2 * qblk + 2;
        const int rowbase = q0 + w * 16;
        const int myq = rowbase + ccol;

        bf16x8 qa[2];
#pragma unroll
        for (int kk = 0; kk < 2; ++kk)
            qa[kk] = *(const bf16x8*)(qb + (size_t)(rowbase + ccol) * DK + kk * 32 + g * 8);

        f32x4 oacc[4] = {};
        float mrow = -1e30f, lpart = 0.f;

        u16x4 vr[4];
        if (w >= 4) {
#pragma unroll
            for (int r2 = 0; r2 < 2; ++r2) {
                int c = r2 * 256 + wk * 64 + lane;
                int row = c >> 3, ch = c & 7;
                __builtin_amdgcn_global_load_lds(
                    (AS1 const void*)(kb + (size_t)row * DK + (ch ^ (row & 7)) * 8),
                    (AS3 void*)(&lK[0][(r2 * 256 + wk * 64) * 8]), 16, 0, 0);
            }
        } else {
#pragma unroll
            for (int i = 0; i < 4; ++i)
                vr[i] = *(const u16x4*)(vb + (size_t)(kg * 4 + i) * DK + dc * 4);
        }

        for (int kt = 0; kt < ntiles; ++kt) {
            const int bf = kt & 1;
            const int kv0 = kt << 6;
            asm volatile("s_waitcnt vmcnt(0)" ::: "memory");
            if (w < 4) {
#pragma unroll
                for (int j = 0; j < 4; ++j) {
                    int d = dc * 4 + j;
                    u16x4 t4;
                    t4[0] = vr[0][j]; t4[1] = vr[1][j]; t4[2] = vr[2][j]; t4[3] = vr[3][j];
                    *(u16x4*)(&lV[bf][d * 64 +
                        (((kg >> 1) ^ ((d >> 1) & 7)) * 8 + (kg & 1) * 4)]) = t4;
                }
            }
            __syncthreads();

            if (kt + 1 < ntiles) {
                const int kvn = (kt + 1) << 6;
                if (w >= 4) {
#pragma unroll
                    for (int r2 = 0; r2 < 2; ++r2) {
                        int c = r2 * 256 + wk * 64 + lane;
                        int row = c >> 3, ch = c & 7;
                        __builtin_amdgcn_global_load_lds(
                            (AS1 const void*)(kb + (size_t)(kvn + row) * DK + (ch ^ (row & 7)) * 8),
                            (AS3 void*)(&lK[bf ^ 1][(r2 * 256 + wk * 64) * 8]), 16, 0, 0);
                    }
                } else {
#pragma unroll
                    for (int i = 0; i < 4; ++i)
                        vr[i] = *(const u16x4*)(vb + (size_t)(kvn + kg * 4 + i) * DK + dc * 4);
                }
            }

            if (kv0 < rowbase + 16) {
                f32x4 sacc[4] = {};
                __builtin_amdgcn_s_setprio(1);
#pragma unroll
                for (int nt = 0; nt < 4; ++nt)
#pragma unroll
                    for (int kk = 0; kk < 2; ++kk) {
                        bf16x8 kf = *(const bf16x8*)(&lK[bf][(nt * 16 + ccol) * 64 +
                                                     (((kk * 4 + g) ^ (ccol & 7)) * 8)]);
                        sacc[nt] = __builtin_amdgcn_mfma_f32_16x16x32_bf16(
                            kf, qa[kk], sacc[nt], 0, 0, 0);
                    }
                __builtin_amdgcn_s_setprio(0);

                const bool full = (kv0 + 63) <= rowbase;
                float mx = -1e30f;
#pragma unroll
                for (int nt = 0; nt < 4; ++nt)
#pragma unroll
                    for (int r = 0; r < 4; ++r) {
                        float sv = sacc[nt][r];
                        if (!full && (kv0 + nt * 16 + g * 4 + r > myq)) sv = -1e30f;
                        sacc[nt][r] = sv;
                        mx = fmaxf(mx, sv);
                    }
                mx = fmaxf(mx, __shfl_xor(mx, 16));
                mx = fmaxf(mx, __shfl_xor(mx, 32));

                const bool skiprow = (mx <= mrow + 8.f);
                float mnew = skiprow ? mrow : mx;
                float p[4][4];
                float rsl = 0.f;
#pragma unroll
                for (int nt = 0; nt < 4; ++nt)
#pragma unroll
                    for (int r = 0; r < 4; ++r) {
                        float pv = __builtin_amdgcn_exp2f(sacc[nt][r] - mnew);
                        p[nt][r] = pv;
                        rsl += pv;
                    }
                float scal = skiprow ? 1.f : __builtin_amdgcn_exp2f(mrow - mnew);
                lpart = lpart * scal + rsl;
                mrow = mnew;

                if (lane < 16) lSc[w][lane] = scal;
                // P pack via v_cvt_pk_bf16_f32 (T12): 8 ops for 16 values
#pragma unroll
                for (int nt = 0; nt < 4; ++nt) {
                    unsigned w0, w1;
                    asm("v_cvt_pk_bf16_f32 %0, %1, %2" : "=v"(w0) : "v"(p[nt][0]), "v"(p[nt][1]));
                    asm("v_cvt_pk_bf16_f32 %0, %1, %2" : "=v"(w1) : "v"(p[nt][2]), "v"(p[nt][3]));
                    uint2 pk; pk.x = w0; pk.y = w1;
                    *(uint2*)(&lP[w][ccol * 72 + nt * 16 + g * 4]) = pk;
                }
                asm volatile("s_waitcnt lgkmcnt(0)" ::: "memory");

                f32x4 scalC = *(const f32x4*)(&lSc[w][g * 4]);
                if (__any(!skiprow)) {
#pragma unroll
                    for (int nt2 = 0; nt2 < 4; ++nt2)
#pragma unroll
                        for (int r = 0; r < 4; ++r) oacc[nt2][r] *= scalC[r];
                }

                bf16x8 pa[2];
#pragma unroll
                for (int kk2 = 0; kk2 < 2; ++kk2)
                    pa[kk2] = *(const bf16x8*)(&lP[w][ccol * 72 + kk2 * 32 + g * 8]);

                const int vsw = (ccol >> 1) & 7;
                __builtin_amdgcn_s_setprio(1);
#pragma unroll
                for (int nt2 = 0; nt2 < 4; ++nt2) {
#pragma unroll
                    for (int kk2 = 0; kk2 < 2; ++kk2) {
                        bf16x8 vf = *(const bf16x8*)(&lV[bf][(nt2 * 16 + ccol) * 64 +
                                                     (((kk2 * 4 + g) ^ vsw) * 8)]);
                        oacc[nt2] = __builtin_amdgcn_mfma_f32_16x16x32_bf16(
                            pa[kk2], vf, oacc[nt2], 0, 0, 0);
                    }
                }
                __builtin_amdgcn_s_setprio(0);
            }
        }
        __syncthreads();

        float rs = lpart;
        rs += __shfl_xor(rs, 16);
        rs += __shfl_xor(rs, 32);
        if (lane < 16) lSc[w][lane] = rs;
        asm volatile("s_waitcnt lgkmcnt(0)" ::: "memory");
        f32x4 rsC = *(const f32x4*)(&lSc[w][g * 4]);
#pragma unroll
        for (int r = 0; r < 4; ++r) {
            float inv = 1.0f / rsC[r];
            int trow = rowbase + g * 4 + r;
#pragma unroll
            for (int nt2 = 0; nt2 < 4; ++nt2) {
                float val = oacc[nt2][r] * inv;
                o[(size_t)(b_ * T_LEN + trow) * D_DIM + h_ * DK + nt2 * 16 + ccol] = f2bf(val);
            }
        }
        __syncthreads();
    }
}

// ---------------- launch ----------------
extern "C" void kernel_launch(void* const* d_in, const int* in_sizes, int n_in,
                              void* d_out, int out_size, void* d_ws, size_t ws_size,
                              hipStream_t stream) {
    const float* x  = (const float*)d_in[0];
    const float* Wq = (const float*)d_in[2];
    const float* Wk = (const float*)d_in[3];
    const float* Wv = (const float*)d_in[4];
    const float* Wo = (const float*)d_in[5];
    const float* bq = (const float*)d_in[6];
    const float* bk = (const float*)d_in[7];
    const float* bv = (const float*)d_in[8];
    const float* bo = (const float*)d_in[9];

    char* ws = (char*)d_ws;
    u16* xb   = (u16*)(ws);                    // 16 MB, reused as attn output
    u16* wqb  = (u16*)(ws + 16777216);         // wq|wk|wv|wo contiguous 2MB each
    u16* wob  = (u16*)(ws + 23068672);
    u16* qws  = (u16*)(ws + 25165824);         // q|k|v contiguous 16MB each
    u16* kws  = (u16*)(ws + 41943040);
    u16* vws  = (u16*)(ws + 58720256);
    u16* attnb = xb;

    cvt_bf16<<<4096, 256, 0, stream>>>(x, xb, 1048576);
    cvt4_bf16<<<dim3(512, 4), 256, 0, stream>>>(Wq, Wk, Wv, Wo, wqb, 131072);

    // fused QKV projection: 768 blocks = 3/CU balanced
    gemm_bp<1, 12><<<768, 512, 0, stream>>>(xb, wqb, bq, bk, bv, qws);

    attn_fwd<<<512, 512, 0, stream>>>(qws, kws, vws, attnb);

    // final projection: 256 blocks = 1/CU balanced
    gemm_bp<0, 4><<<256, 512, 0, stream>>>(attnb, wob, bo, bo, bo, d_out);
}

// Round 10
// 294.797 us; speedup vs baseline: 1.0167x; 1.0167x over previous
//
#include <hip/hip_runtime.h>
#include <hip/hip_bf16.h>

#define T_LEN 2048
#define D_DIM 1024
#define H_NUM 16
#define DK 64

typedef unsigned short u16;
typedef __bf16 bf16x8 __attribute__((ext_vector_type(8)));
typedef float f32x4 __attribute__((ext_vector_type(4)));
typedef u16 u16x8 __attribute__((ext_vector_type(8)));
typedef u16 u16x4 __attribute__((ext_vector_type(4)));

#define AS1 __attribute__((address_space(1)))
#define AS3 __attribute__((address_space(3)))

// Q pre-scale: 1/sqrt(64) * log2(e)  (softmax done in exp2 domain)
#define QSCALE 0.18033688011112042f

__device__ __forceinline__ u16 f2bf(float f) {
    unsigned u = __builtin_bit_cast(unsigned, f);
    unsigned rounding = 0x7FFFu + ((u >> 16) & 1u);
    return (u16)((u + rounding) >> 16);
}

// ---------------- f32 -> bf16 conversion (8 elems / thread) ----------------
__global__ __launch_bounds__(256) void cvt_bf16(const float* __restrict__ in,
                                                u16* __restrict__ out, int n8) {
    int i = blockIdx.x * blockDim.x + threadIdx.x;
    if (i >= n8) return;
    const float4* p = (const float4*)in + (size_t)i * 2;
    float4 a = p[0], b = p[1];
    u16x8 r;
    r[0] = f2bf(a.x); r[1] = f2bf(a.y); r[2] = f2bf(a.z); r[3] = f2bf(a.w);
    r[4] = f2bf(b.x); r[5] = f2bf(b.y); r[6] = f2bf(b.z); r[7] = f2bf(b.w);
    *((u16x8*)out + i) = r;
}

__global__ __launch_bounds__(256) void cvt4_bf16(const float* __restrict__ a,
                                                 const float* __restrict__ b,
                                                 const float* __restrict__ c,
                                                 const float* __restrict__ d,
                                                 u16* __restrict__ out, int n8per) {
    int s = blockIdx.y;
    const float* src = s == 0 ? a : (s == 1 ? b : (s == 2 ? c : d));
    int i = blockIdx.x * blockDim.x + threadIdx.x;
    if (i >= n8per) return;
    const float4* p = (const float4*)src + (size_t)i * 2;
    float4 x = p[0], y = p[1];
    u16x8 r;
    r[0] = f2bf(x.x); r[1] = f2bf(x.y); r[2] = f2bf(x.z); r[3] = f2bf(x.w);
    r[4] = f2bf(y.x); r[5] = f2bf(y.y); r[6] = f2bf(y.z); r[7] = f2bf(y.w);
    *((u16x8*)(out + (size_t)s * n8per * 8) + i) = r;
}

// ======= QKV GEMM: 256x192 tile, BK=64 (2 kk), 8 waves, 4-phase pipeline ====
// C[8192, 3072] = A * W^T + bias -> bf16 [mtx][B,H,T,DK], q pre-scaled.
// Grid 512 = 32m x 16n -> exactly 2 clean rounds at 1 block/CU (no idle tail).
// LDS: LA[2par][2kk][256x32]=64KB + LB[2][2][192x32]=48KB = 112 KB.
// Phase p: kk=p>>1, M-quadrant mh=(p&1)*4. 12 MFMA/phase. Stage slots:
// p0:A-kk1(t+1) p1:B-kk1(t+1) p2:A-kk0(t+2) p3:B-kk0(t+2)+vmcnt(4|0).
// B staging wave-uniform (2 loads/thread; 2nd issue duplicated across hi waves)
// so the per-wave vmcnt ledger is identical for all waves (r8-proven ledger).
__global__ __launch_bounds__(512) void gemm_qkv192(const u16* __restrict__ A,
                                                   const u16* __restrict__ W,
                                                   const float* __restrict__ b0,
                                                   const float* __restrict__ b1,
                                                   const float* __restrict__ b2,
                                                   u16* __restrict__ Cout) {
    __shared__ u16 LA[2][2][8192];   // [par][kk][256 rows x 32 k]
    __shared__ u16 LB[2][2][6144];   // [par][kk][192 rows x 32 k]
    const int tid = threadIdx.x, w = tid >> 6, lane = tid & 63;
    const int sw = (blockIdx.x & 7) * 64 + (blockIdx.x >> 3);  // XCD-chunked
    const int xm = sw >> 4, yn = sw & 15;
    const int tm = xm * 256, tn = yn * 192;
    const int wr = w >> 2, wc = w & 3;          // 2M x 4N wave grid
    const int g = lane >> 4, ccol = lane & 15;
    const int gsw = (g ^ ((ccol >> 1) & 3)) * 8;   // read-side swizzle
    const int NT = 16;

    f32x4 acc[8][3] = {};

    auto stageA = [&](u16* dst, int kcol) {      // 256x32 half (16 KB)
#pragma unroll
        for (int h = 0; h < 2; ++h) {
            int c = h * 512 + tid;
            int row = c >> 2;
            int kc = ((c & 3) ^ ((row >> 1) & 3)) * 8;
            __builtin_amdgcn_global_load_lds(
                (AS1 const void*)(A + (size_t)(tm + row) * 1024 + kcol + kc),
                (AS3 void*)(dst + h * 4096 + w * 512), 16, 0, 0);
        }
    };
    auto stageB = [&](u16* dst, int kcol) {      // 192x32 half (12 KB)
        {
            int c = tid, row = c >> 2;
            int kc = ((c & 3) ^ ((row >> 1) & 3)) * 8;
            __builtin_amdgcn_global_load_lds(
                (AS1 const void*)(W + (size_t)(tn + row) * 1024 + kcol + kc),
                (AS3 void*)(dst + w * 512), 16, 0, 0);
        }
        {   // rows 128..191; waves 4-7 duplicate waves 0-3 (same data, uniform count)
            int c = 512 + (tid & 255), row = c >> 2;
            int kc = ((c & 3) ^ ((row >> 1) & 3)) * 8;
            __builtin_amdgcn_global_load_lds(
                (AS1 const void*)(W + (size_t)(tn + row) * 1024 + kcol + kc),
                (AS3 void*)(dst + 4096 + (w & 3) * 512), 16, 0, 0);
        }
    };

    // prologue: kk0(t0), kk1(t0), kk0(t1) -- 12 loads/thread, oldest-first
    stageA(LA[0][0], 0);  stageB(LB[0][0], 0);
    stageA(LA[0][1], 32); stageB(LB[0][1], 32);
    stageA(LA[1][0], 64); stageB(LB[1][0], 64);
    asm volatile("s_waitcnt vmcnt(4)" ::: "memory");   // t0 both halves complete
    __builtin_amdgcn_s_barrier();

    bf16x8 bfr[3];
    for (int t = 0; t < NT; ++t) {
        const int par = t & 1;
#pragma unroll
        for (int p = 0; p < 4; ++p) {
            const int kk = p >> 1, mh = (p & 1) * 4;
            const u16* LAp = LA[par][kk];
            const u16* LBp = LB[par][kk];
            bf16x8 af[4];
#pragma unroll
            for (int i = 0; i < 4; ++i)
                af[i] = *(const bf16x8*)(LAp + (wr * 128 + (mh + i) * 16 + ccol) * 32 + gsw);
            if ((p & 1) == 0) {
#pragma unroll
                for (int i = 0; i < 3; ++i)
                    bfr[i] = *(const bf16x8*)(LBp + (wc * 48 + i * 16 + ccol) * 32 + gsw);
            }
            // stage one half into the region whose readers passed the last barrier
            if (p == 0)      { if (t + 1 < NT) stageA(LA[par ^ 1][1], (t + 1) * 64 + 32); }
            else if (p == 1) { if (t + 1 < NT) stageB(LB[par ^ 1][1], (t + 1) * 64 + 32); }
            else if (p == 2) { if (t + 2 < NT) stageA(LA[par][0], (t + 2) * 64); }
            else {
                if (t + 2 < NT) stageB(LB[par][0], (t + 2) * 64);
                if (t < NT - 2) asm volatile("s_waitcnt vmcnt(4)" ::: "memory");
                else            asm volatile("s_waitcnt vmcnt(0)" ::: "memory");
            }
            __builtin_amdgcn_s_barrier();
            asm volatile("s_waitcnt lgkmcnt(0)" ::: "memory");
            __builtin_amdgcn_sched_barrier(0);
            __builtin_amdgcn_s_setprio(1);
#pragma unroll
            for (int mi = 0; mi < 4; ++mi)
#pragma unroll
                for (int ni = 0; ni < 3; ++ni)
                    acc[mh + mi][ni] = __builtin_amdgcn_mfma_f32_16x16x32_bf16(
                        af[mi], bfr[ni], acc[mh + mi][ni], 0, 0, 0);
            __builtin_amdgcn_s_setprio(0);
            __builtin_amdgcn_s_barrier();
        }
    }

    // epilogue: bias + permute to [mtx][B,H,T,DK] (per-ni panel decode; tiles
    // may straddle the q/k/v boundary but 16-wide frags never do)
#pragma unroll
    for (int ni = 0; ni < 3; ++ni) {
        const int n0 = tn + wc * 48 + ni * 16;
        const int mtx = n0 >> 10;
        const float* bp = mtx == 0 ? b0 : (mtx == 1 ? b1 : b2);
        const int nn = (n0 + ccol) & 1023;
        const float bv = bp[nn];
        const int h = nn >> 6, d = nn & 63;
#pragma unroll
        for (int mi = 0; mi < 8; ++mi) {
#pragma unroll
            for (int r = 0; r < 4; ++r) {
                int m = tm + wr * 128 + mi * 16 + g * 4 + r;
                float val = acc[mi][ni][r] + bv;
                if (mtx == 0) val *= QSCALE;
                int b = m >> 11, tt = m & (T_LEN - 1);
                Cout[(size_t)mtx * 8388608 +
                     ((size_t)(b * H_NUM + h) * T_LEN + tt) * DK + d] = f2bf(val);
            }
        }
    }
}

// ---------------- GEMM (final projection): 128x128, 2-phase ----------------
__global__ __launch_bounds__(256) void gemm_bt(const u16* __restrict__ A,
                                               const u16* __restrict__ W,
                                               const float* __restrict__ b0,
                                               float* __restrict__ Cout,
                                               int M, int N, int K,
                                               int nxt, int nyt) {
    __shared__ u16 lA[2][128 * 32];
    __shared__ u16 lB[2][128 * 32];
    const int tid = threadIdx.x;
    const int w = tid >> 6, lane = tid & 63;

    const int bid = blockIdx.x;
    const int idx = bid >> 3;
    const int y = idx % nyt;
    const int x = (bid & 7) * (nxt >> 3) + idx / nyt;
    const int tm = x * 128;
    const int tn = y * 128;

    const int wm = (w >> 1) * 64, wn = (w & 1) * 64;
    const int kgrp = (lane >> 4) * 8;

    f32x4 acc[4][4] = {};

    auto stage = [&](int buf, int k0) {
#pragma unroll
        for (int r = 0; r < 2; ++r) {
            int c = r * 256 + tid;
            int row = c >> 2, col = (c & 3) * 8;
            __builtin_amdgcn_global_load_lds(
                (AS1 const void*)(A + (size_t)(tm + row) * K + k0 + col),
                (AS3 void*)(&lA[buf][(r * 256 + w * 64) * 8]), 16, 0, 0);
            __builtin_amdgcn_global_load_lds(
                (AS1 const void*)(W + (size_t)(tn + row) * K + k0 + col),
                (AS3 void*)(&lB[buf][(r * 256 + w * 64) * 8]), 16, 0, 0);
        }
    };

    stage(0, 0);
    asm volatile("s_waitcnt vmcnt(0)" ::: "memory");
    __syncthreads();

    const int niter = K >> 5;
    for (int it = 0; it < niter; ++it) {
        const int cur = it & 1;
        if (it + 1 < niter) stage(cur ^ 1, (it + 1) << 5);

        bf16x8 af[4], bfr[4];
#pragma unroll
        for (int i = 0; i < 4; ++i) {
            af[i]  = *(const bf16x8*)(&lA[cur][(wm + i * 16 + (lane & 15)) * 32 + kgrp]);
            bfr[i] = *(const bf16x8*)(&lB[cur][(wn + i * 16 + (lane & 15)) * 32 + kgrp]);
        }
#pragma unroll
        for (int mi = 0; mi < 4; ++mi)
#pragma unroll
            for (int ni = 0; ni < 4; ++ni)
                acc[mi][ni] = __builtin_amdgcn_mfma_f32_16x16x32_bf16(
                    af[mi], bfr[ni], acc[mi][ni], 0, 0, 0);

        asm volatile("s_waitcnt vmcnt(0)" ::: "memory");
        __syncthreads();
    }

    const int crow0 = (lane >> 4) * 4;
    const int ccol = lane & 15;
#pragma unroll
    for (int mi = 0; mi < 4; ++mi) {
#pragma unroll
        for (int ni = 0; ni < 4; ++ni) {
            int n = tn + wn + ni * 16 + ccol;
            float bv = b0[n & 1023];
#pragma unroll
            for (int r = 0; r < 4; ++r) {
                int m = tm + wm + mi * 16 + crow0 + r;
                Cout[(size_t)m * N + n] = acc[mi][ni][r] + bv;
            }
        }
    }
}

// ---------------- Flash attention, causal ----------------
// grid 512 (XCD-decoded), block 512 (8 waves). Block handles q-block pair
// {bx, 15-bx} of 128 rows; wave w owns 16 rows. KV tile 64, double-buffered.
// SWAPPED QK^T: S^T = mfma(K, Q) -> each lane holds 16 S-values for ONE q.
__global__ __launch_bounds__(512) void attn_fwd(const u16* __restrict__ q,
                                                const u16* __restrict__ k,
                                                const u16* __restrict__ v,
                                                u16* __restrict__ o) {
    __shared__ u16 lK[2][64 * 64];     // [key][d], 16B-window ^= key&7
    __shared__ u16 lV[2][64 * 64];     // [d][key], 16B-window ^= (d>>1)&7
    __shared__ u16 lP[8][16 * 72];     // per-wave P, row stride 144B
    __shared__ float lSc[8][16];       // softmax-layout -> C-layout relay

    const int tid = threadIdx.x, w = tid >> 6, lane = tid & 63;
    const int bid = blockIdx.x;
    const int idx = bid >> 3;
    const int bh = (bid & 7) * 8 + (idx & 7);    // 8 bh per XCD
    const int bx = idx >> 3;

    const u16* qb = q + (size_t)bh * T_LEN * DK;
    const u16* kb = k + (size_t)bh * T_LEN * DK;
    const u16* vb = v + (size_t)bh * T_LEN * DK;

    const int g = lane >> 4;
    const int ccol = lane & 15;
    const int kg = tid >> 4;
    const int dc = tid & 15;
    const int wk = w - 4;
    const int b_ = bh >> 4, h_ = bh & 15;

    for (int seg = 0; seg < 2; ++seg) {
        const int qblk = seg ? (15 - bx) : bx;
        const int q0 = qblk * 128;
        const int ntiles = 2 * qblk + 2;
        const int rowbase = q0 + w * 16;
        const int myq = rowbase + ccol;

        bf16x8 qa[2];
#pragma unroll
        for (int kk = 0; kk < 2; ++kk)
            qa[kk] = *(const bf16x8*)(qb + (size_t)(rowbase + ccol) * DK + kk * 32 + g * 8);

        f32x4 oacc[4] = {};
        float mrow = -1e30f, lpart = 0.f;

        u16x4 vr[4];
        if (w >= 4) {
#pragma unroll
            for (int r2 = 0; r2 < 2; ++r2) {
                int c = r2 * 256 + wk * 64 + lane;
                int row = c >> 3, ch = c & 7;
                __builtin_amdgcn_global_load_lds(
                    (AS1 const void*)(kb + (size_t)row * DK + (ch ^ (row & 7)) * 8),
                    (AS3 void*)(&lK[0][(r2 * 256 + wk * 64) * 8]), 16, 0, 0);
            }
        } else {
#pragma unroll
            for (int i = 0; i < 4; ++i)
                vr[i] = *(const u16x4*)(vb + (size_t)(kg * 4 + i) * DK + dc * 4);
        }

        for (int kt = 0; kt < ntiles; ++kt) {
            const int bf = kt & 1;
            const int kv0 = kt << 6;
            asm volatile("s_waitcnt vmcnt(0)" ::: "memory");
            if (w < 4) {
#pragma unroll
                for (int j = 0; j < 4; ++j) {
                    int d = dc * 4 + j;
                    u16x4 t4;
                    t4[0] = vr[0][j]; t4[1] = vr[1][j]; t4[2] = vr[2][j]; t4[3] = vr[3][j];
                    *(u16x4*)(&lV[bf][d * 64 +
                        (((kg >> 1) ^ ((d >> 1) & 7)) * 8 + (kg & 1) * 4)]) = t4;
                }
            }
            __syncthreads();

            if (kt + 1 < ntiles) {
                const int kvn = (kt + 1) << 6;
                if (w >= 4) {
#pragma unroll
                    for (int r2 = 0; r2 < 2; ++r2) {
                        int c = r2 * 256 + wk * 64 + lane;
                        int row = c >> 3, ch = c & 7;
                        __builtin_amdgcn_global_load_lds(
                            (AS1 const void*)(kb + (size_t)(kvn + row) * DK + (ch ^ (row & 7)) * 8),
                            (AS3 void*)(&lK[bf ^ 1][(r2 * 256 + wk * 64) * 8]), 16, 0, 0);
                    }
                } else {
#pragma unroll
                    for (int i = 0; i < 4; ++i)
                        vr[i] = *(const u16x4*)(vb + (size_t)(kvn + kg * 4 + i) * DK + dc * 4);
                }
            }

            if (kv0 < rowbase + 16) {
                f32x4 sacc[4] = {};
                __builtin_amdgcn_s_setprio(1);
#pragma unroll
                for (int nt = 0; nt < 4; ++nt)
#pragma unroll
                    for (int kk = 0; kk < 2; ++kk) {
                        bf16x8 kf = *(const bf16x8*)(&lK[bf][(nt * 16 + ccol) * 64 +
                                                     (((kk * 4 + g) ^ (ccol & 7)) * 8)]);
                        sacc[nt] = __builtin_amdgcn_mfma_f32_16x16x32_bf16(
                            kf, qa[kk], sacc[nt], 0, 0, 0);
                    }
                __builtin_amdgcn_s_setprio(0);

                const bool full = (kv0 + 63) <= rowbase;
                float mx = -1e30f;
#pragma unroll
                for (int nt = 0; nt < 4; ++nt)
#pragma unroll
                    for (int r = 0; r < 4; ++r) {
                        float sv = sacc[nt][r];
                        if (!full && (kv0 + nt * 16 + g * 4 + r > myq)) sv = -1e30f;
                        sacc[nt][r] = sv;
                        mx = fmaxf(mx, sv);
                    }
                mx = fmaxf(mx, __shfl_xor(mx, 16));
                mx = fmaxf(mx, __shfl_xor(mx, 32));

                const bool skiprow = (mx <= mrow + 8.f);
                float mnew = skiprow ? mrow : mx;
                float p[4][4];
                float rsl = 0.f;
#pragma unroll
                for (int nt = 0; nt < 4; ++nt)
#pragma unroll
                    for (int r = 0; r < 4; ++r) {
                        float pv = __builtin_amdgcn_exp2f(sacc[nt][r] - mnew);
                        p[nt][r] = pv;
                        rsl += pv;
                    }
                float scal = skiprow ? 1.f : __builtin_amdgcn_exp2f(mrow - mnew);
                lpart = lpart * scal + rsl;
                mrow = mnew;

                if (lane < 16) lSc[w][lane] = scal;
#pragma unroll
                for (int nt = 0; nt < 4; ++nt) {
                    u16x4 t4;
                    t4[0] = f2bf(p[nt][0]); t4[1] = f2bf(p[nt][1]);
                    t4[2] = f2bf(p[nt][2]); t4[3] = f2bf(p[nt][3]);
                    *(u16x4*)(&lP[w][ccol * 72 + nt * 16 + g * 4]) = t4;
                }
                asm volatile("s_waitcnt lgkmcnt(0)" ::: "memory");

                f32x4 scalC = *(const f32x4*)(&lSc[w][g * 4]);
                if (__any(!skiprow)) {
#pragma unroll
                    for (int nt2 = 0; nt2 < 4; ++nt2)
#pragma unroll
                        for (int r = 0; r < 4; ++r) oacc[nt2][r] *= scalC[r];
                }

                bf16x8 pa[2];
#pragma unroll
                for (int kk2 = 0; kk2 < 2; ++kk2)
                    pa[kk2] = *(const bf16x8*)(&lP[w][ccol * 72 + kk2 * 32 + g * 8]);

                const int vsw = (ccol >> 1) & 7;
                __builtin_amdgcn_s_setprio(1);
#pragma unroll
                for (int nt2 = 0; nt2 < 4; ++nt2) {
#pragma unroll
                    for (int kk2 = 0; kk2 < 2; ++kk2) {
                        bf16x8 vf = *(const bf16x8*)(&lV[bf][(nt2 * 16 + ccol) * 64 +
                                                     (((kk2 * 4 + g) ^ vsw) * 8)]);
                        oacc[nt2] = __builtin_amdgcn_mfma_f32_16x16x32_bf16(
                            pa[kk2], vf, oacc[nt2], 0, 0, 0);
                    }
                }
                __builtin_amdgcn_s_setprio(0);
            }
        }
        __syncthreads();

        float rs = lpart;
        rs += __shfl_xor(rs, 16);
        rs += __shfl_xor(rs, 32);
        if (lane < 16) lSc[w][lane] = rs;
        asm volatile("s_waitcnt lgkmcnt(0)" ::: "memory");
        f32x4 rsC = *(const f32x4*)(&lSc[w][g * 4]);
#pragma unroll
        for (int r = 0; r < 4; ++r) {
            float inv = 1.0f / rsC[r];
            int trow = rowbase + g * 4 + r;
#pragma unroll
            for (int nt2 = 0; nt2 < 4; ++nt2) {
                float val = oacc[nt2][r] * inv;
                o[(size_t)(b_ * T_LEN + trow) * D_DIM + h_ * DK + nt2 * 16 + ccol] = f2bf(val);
            }
        }
        __syncthreads();
    }
}

// ---------------- launch ----------------
extern "C" void kernel_launch(void* const* d_in, const int* in_sizes, int n_in,
                              void* d_out, int out_size, void* d_ws, size_t ws_size,
                              hipStream_t stream) {
    const float* x  = (const float*)d_in[0];
    const float* Wq = (const float*)d_in[2];
    const float* Wk = (const float*)d_in[3];
    const float* Wv = (const float*)d_in[4];
    const float* Wo = (const float*)d_in[5];
    const float* bq = (const float*)d_in[6];
    const float* bk = (const float*)d_in[7];
    const float* bv = (const float*)d_in[8];
    const float* bo = (const float*)d_in[9];

    char* ws = (char*)d_ws;
    u16* xb   = (u16*)(ws);                    // 16 MB, reused as attn output
    u16* wqb  = (u16*)(ws + 16777216);         // wq|wk|wv|wo contiguous 2MB each
    u16* wob  = (u16*)(ws + 23068672);
    u16* qws  = (u16*)(ws + 25165824);         // q|k|v contiguous 16MB each
    u16* kws  = (u16*)(ws + 41943040);
    u16* vws  = (u16*)(ws + 58720256);
    u16* attnb = xb;

    cvt_bf16<<<4096, 256, 0, stream>>>(x, xb, 1048576);
    cvt4_bf16<<<dim3(512, 4), 256, 0, stream>>>(Wq, Wk, Wv, Wo, wqb, 131072);

    // fused QKV projection: 512 blocks = exactly 2 clean rounds
    gemm_qkv192<<<512, 512, 0, stream>>>(xb, wqb, bq, bk, bv, qws);

    attn_fwd<<<512, 512, 0, stream>>>(qws, kws, vws, attnb);

    gemm_bt<<<512, 256, 0, stream>>>(attnb, wob, bo, (float*)d_out, 8192, 1024, 1024, 64, 8);
}

// Round 11
// 273.474 us; speedup vs baseline: 1.0960x; 1.0780x over previous
//
#include <hip/hip_runtime.h>
#include <hip/hip_bf16.h>

#define T_LEN 2048
#define D_DIM 1024
#define H_NUM 16
#define DK 64

typedef unsigned short u16;
typedef __bf16 bf16x8 __attribute__((ext_vector_type(8)));
typedef float f32x4 __attribute__((ext_vector_type(4)));
typedef u16 u16x8 __attribute__((ext_vector_type(8)));
typedef u16 u16x4 __attribute__((ext_vector_type(4)));

#define AS1 __attribute__((address_space(1)))
#define AS3 __attribute__((address_space(3)))

// Q pre-scale: 1/sqrt(64) * log2(e)  (softmax done in exp2 domain)
#define QSCALE 0.18033688011112042f

__device__ __forceinline__ u16 f2bf(float f) {
    unsigned u = __builtin_bit_cast(unsigned, f);
    unsigned rounding = 0x7FFFu + ((u >> 16) & 1u);
    return (u16)((u + rounding) >> 16);
}

// -------- fused f32 -> bf16 conversion: x (8M elems) + 4 weights (1M each) --
__global__ __launch_bounds__(256) void cvt_all(const float* __restrict__ x,
                                               const float* __restrict__ wq,
                                               const float* __restrict__ wk,
                                               const float* __restrict__ wv,
                                               const float* __restrict__ wo,
                                               u16* __restrict__ xb,
                                               u16* __restrict__ wb) {
    int i = blockIdx.x * 256 + threadIdx.x;     // 8-elem unit; total 1572864
    const float* src; u16* dst; int off;
    if (i < 1048576) { src = x; dst = xb; off = i; }
    else {
        int j = i - 1048576;
        int s = j >> 17; off = j & 131071;
        src = s == 0 ? wq : (s == 1 ? wk : (s == 2 ? wv : wo));
        dst = wb + (size_t)s * 1048576;
    }
    const float4* p = (const float4*)src + (size_t)off * 2;
    float4 a = p[0], b = p[1];
    u16x8 r;
    r[0] = f2bf(a.x); r[1] = f2bf(a.y); r[2] = f2bf(a.z); r[3] = f2bf(a.w);
    r[4] = f2bf(b.x); r[5] = f2bf(b.y); r[6] = f2bf(b.z); r[7] = f2bf(b.w);
    *((u16x8*)dst + off) = r;
}

// ============ QKV GEMM: 256x256 tile, BK=64, 8 waves, 8-phase (r8-proven) ===
__global__ __launch_bounds__(512) void gemm_qkv(const u16* __restrict__ A,
                                                const u16* __restrict__ W,
                                                const float* __restrict__ b0,
                                                const float* __restrict__ b1,
                                                const float* __restrict__ b2,
                                                u16* __restrict__ Cout) {
    __shared__ u16 L[2][4][8192];   // [parity][A0,A1,B0,B1][256 rows x 32 k]
    const int tid = threadIdx.x, w = tid >> 6, lane = tid & 63;
    const int sw = (blockIdx.x & 7) * 48 + (blockIdx.x >> 3);  // XCD-chunked
    const int xm = sw / 12, yn = sw % 12;
    const int tm = xm * 256, tn = yn * 256;
    const int wr = w >> 2, wc = w & 3;          // wave grid 2M x 4N
    const int g = lane >> 4, ccol = lane & 15;
    const int gsw = (g ^ ((ccol >> 1) & 3)) * 8;   // read-side swizzle
    const int K = 1024, NT = 16;

    const u16* Ab = A + (size_t)tm * K;
    const u16* Wb = W + (size_t)tn * K;

    const int srow = w * 16 + (lane >> 2);
    const int skk  = (((lane & 3) ^ ((lane >> 3) & 3))) * 8;  // inverse swizzle

    f32x4 acc[8][4] = {};

    auto stage = [&](const u16* gb, int k0, int ksub, u16* reg) {
#pragma unroll
        for (int h2 = 0; h2 < 2; ++h2) {
            __builtin_amdgcn_global_load_lds(
                (AS1 const void*)(gb + (size_t)(h2 * 128 + srow) * K + k0 + ksub * 32 + skk),
                (AS3 void*)(reg + h2 * 4096 + w * 512), 16, 0, 0);
        }
    };

    stage(Ab, 0, 0, L[0][0]);
    stage(Wb, 0, 0, L[0][2]);
    stage(Ab, 0, 1, L[0][1]);
    stage(Wb, 0, 1, L[0][3]);
    stage(Ab, 64, 0, L[1][0]);
    stage(Wb, 64, 0, L[1][2]);
    asm volatile("s_waitcnt vmcnt(4)" ::: "memory");   // tile0 forced complete
    __builtin_amdgcn_s_barrier();

    bf16x8 bfr[4];
    for (int t = 0; t < NT; ++t) {
        const int par = t & 1;
        u16* LA0 = L[par][0]; u16* LA1 = L[par][1];
        u16* LB0 = L[par][2]; u16* LB1 = L[par][3];
#pragma unroll
        for (int p = 0; p < 4; ++p) {
            const int mh = (p & 1) * 4;
            u16* LAk = (p >> 1) ? LA1 : LA0;
            u16* LBk = (p >> 1) ? LB1 : LB0;
            bf16x8 af[4];
#pragma unroll
            for (int i = 0; i < 4; ++i)
                af[i] = *(const bf16x8*)(LAk + (wr * 128 + (mh + i) * 16 + ccol) * 32 + gsw);
            if ((p & 1) == 0) {
#pragma unroll
                for (int i = 0; i < 4; ++i)
                    bfr[i] = *(const bf16x8*)(LBk + (wc * 64 + i * 16 + ccol) * 32 + gsw);
            }
            if (p == 0)      { if (t + 1 < NT) stage(Ab, (t + 1) * 64, 1, L[(t + 1) & 1][1]); }
            else if (p == 1) { if (t + 1 < NT) stage(Wb, (t + 1) * 64, 1, L[(t + 1) & 1][3]); }
            else if (p == 2) { if (t + 2 < NT) stage(Ab, (t + 2) * 64, 0, L[par][0]); }
            else {
                if (t + 2 < NT) stage(Wb, (t + 2) * 64, 0, L[par][2]);
                if (t < NT - 2) asm volatile("s_waitcnt vmcnt(4)" ::: "memory");
                else            asm volatile("s_waitcnt vmcnt(0)" ::: "memory");
            }
            __builtin_amdgcn_s_barrier();
            asm volatile("s_waitcnt lgkmcnt(0)" ::: "memory");
            __builtin_amdgcn_sched_barrier(0);
            __builtin_amdgcn_s_setprio(1);
#pragma unroll
            for (int ni = 0; ni < 4; ++ni)
#pragma unroll
                for (int mi = 0; mi < 4; ++mi)
                    acc[mh + mi][ni] = __builtin_amdgcn_mfma_f32_16x16x32_bf16(
                        af[mi], bfr[ni], acc[mh + mi][ni], 0, 0, 0);
            __builtin_amdgcn_s_setprio(0);
            __builtin_amdgcn_s_barrier();
        }
    }

    const int mtx = yn >> 2;
    const float* bp = mtx == 0 ? b0 : (mtx == 1 ? b1 : b2);
#pragma unroll
    for (int mi = 0; mi < 8; ++mi) {
#pragma unroll
        for (int ni = 0; ni < 4; ++ni) {
            int nn = (tn + wc * 64 + ni * 16 + ccol) & 1023;
            float bv = bp[nn];
            int h = nn >> 6, d = nn & 63;
#pragma unroll
            for (int r = 0; r < 4; ++r) {
                int m = tm + wr * 128 + mi * 16 + g * 4 + r;
                float val = acc[mi][ni][r] + bv;
                if (mtx == 0) val *= QSCALE;
                int b = m >> 11, tt = m & (T_LEN - 1);
                Cout[(size_t)mtx * 8388608 +
                     ((size_t)(b * H_NUM + h) * T_LEN + tt) * DK + d] = f2bf(val);
            }
        }
    }
}

// ===== Final projection: 256x128 tile, BK=64 (2 kk), 8 waves, pipelined =====
// C[8192,1024] f32 = A * Wo^T + bo. Grid 32m x 8n = 256 blocks = 1 clean round.
// LDS: LA[2par][2kk][256x32]=64KB + LB[2][2][128x32]=32KB = 96 KB.
// Waves 4M x 2N -> 64x64 per wave (acc 64 AGPR; full-sector 256B row writes).
// Per tile: 2 phases (kk). Stage: p0: A1,B1(t+1) [3]; p1: A0,B0(t+2) [3] +
// vmcnt(3) steady / vmcnt(0) tail (ledger: wait leaves newest 3).
__global__ __launch_bounds__(512) void gemm_o(const u16* __restrict__ A,
                                              const u16* __restrict__ W,
                                              const float* __restrict__ b0,
                                              float* __restrict__ Cout) {
    __shared__ u16 LA[2][2][8192];
    __shared__ u16 LB[2][2][4096];
    const int tid = threadIdx.x, w = tid >> 6, lane = tid & 63;
    const int sw = (blockIdx.x & 7) * 32 + (blockIdx.x >> 3);  // XCD-chunked
    const int xm = sw >> 3, yn = sw & 7;
    const int tm = xm * 256, tn = yn * 128;
    const int wr = w >> 1, wc = w & 1;          // wave grid 4M x 2N
    const int g = lane >> 4, ccol = lane & 15;
    const int gsw = (g ^ ((ccol >> 1) & 3)) * 8;
    const int NT = 16;

    f32x4 acc[4][4] = {};

    auto stageA = [&](u16* dst, int kcol) {     // 256x32 half (16 KB, 2/thread)
#pragma unroll
        for (int h = 0; h < 2; ++h) {
            int c = h * 512 + tid;
            int row = c >> 2;
            int kc = ((c & 3) ^ ((row >> 1) & 3)) * 8;
            __builtin_amdgcn_global_load_lds(
                (AS1 const void*)(A + (size_t)(tm + row) * 1024 + kcol + kc),
                (AS3 void*)(dst + h * 4096 + w * 512), 16, 0, 0);
        }
    };
    auto stageB = [&](u16* dst, int kcol) {     // 128x32 half (8 KB, 1/thread)
        int row = tid >> 2;
        int kc = ((tid & 3) ^ ((row >> 1) & 3)) * 8;
        __builtin_amdgcn_global_load_lds(
            (AS1 const void*)(W + (size_t)(tn + row) * 1024 + kcol + kc),
            (AS3 void*)(dst + w * 512), 16, 0, 0);
    };

    // prologue: kk0(t0), kk1(t0), kk0(t1) -- 9 loads/thread, oldest-first
    stageA(LA[0][0], 0);  stageB(LB[0][0], 0);
    stageA(LA[0][1], 32); stageB(LB[0][1], 32);
    stageA(LA[1][0], 64); stageB(LB[1][0], 64);
    asm volatile("s_waitcnt vmcnt(3)" ::: "memory");
    __builtin_amdgcn_s_barrier();

    for (int t = 0; t < NT; ++t) {
        const int par = t & 1;
#pragma unroll
        for (int p = 0; p < 2; ++p) {
            const u16* LAp = LA[par][p];
            const u16* LBp = LB[par][p];
            bf16x8 af[4], bfr[4];
#pragma unroll
            for (int i = 0; i < 4; ++i) {
                af[i]  = *(const bf16x8*)(LAp + (wr * 64 + i * 16 + ccol) * 32 + gsw);
                bfr[i] = *(const bf16x8*)(LBp + (wc * 64 + i * 16 + ccol) * 32 + gsw);
            }
            if (p == 0) {
                if (t + 1 < NT) { stageA(LA[par ^ 1][1], (t + 1) * 64 + 32);
                                  stageB(LB[par ^ 1][1], (t + 1) * 64 + 32); }
            } else {
                if (t + 2 < NT) { stageA(LA[par][0], (t + 2) * 64);
                                  stageB(LB[par][0], (t + 2) * 64); }
                if (t < NT - 2) asm volatile("s_waitcnt vmcnt(3)" ::: "memory");
                else            asm volatile("s_waitcnt vmcnt(0)" ::: "memory");
            }
            __builtin_amdgcn_s_barrier();
            asm volatile("s_waitcnt lgkmcnt(0)" ::: "memory");
            __builtin_amdgcn_sched_barrier(0);
            __builtin_amdgcn_s_setprio(1);
#pragma unroll
            for (int mi = 0; mi < 4; ++mi)
#pragma unroll
                for (int ni = 0; ni < 4; ++ni)
                    acc[mi][ni] = __builtin_amdgcn_mfma_f32_16x16x32_bf16(
                        af[mi], bfr[ni], acc[mi][ni], 0, 0, 0);
            __builtin_amdgcn_s_setprio(0);
            __builtin_amdgcn_s_barrier();
        }
    }

    // epilogue: full-sector f32 rows (64 consecutive n per wave)
#pragma unroll
    for (int mi = 0; mi < 4; ++mi) {
#pragma unroll
        for (int ni = 0; ni < 4; ++ni) {
            int n = tn + wc * 64 + ni * 16 + ccol;
            float bv = b0[n];
#pragma unroll
            for (int r = 0; r < 4; ++r) {
                int m = tm + wr * 64 + mi * 16 + g * 4 + r;
                Cout[(size_t)m * 1024 + n] = acc[mi][ni][r] + bv;
            }
        }
    }
}

// ---------------- Flash attention, causal (r8-proven) ----------------
__global__ __launch_bounds__(512) void attn_fwd(const u16* __restrict__ q,
                                                const u16* __restrict__ k,
                                                const u16* __restrict__ v,
                                                u16* __restrict__ o) {
    __shared__ u16 lK[2][64 * 64];     // [key][d], 16B-window ^= key&7
    __shared__ u16 lV[2][64 * 64];     // [d][key], 16B-window ^= (d>>1)&7
    __shared__ u16 lP[8][16 * 72];     // per-wave P, row stride 144B
    __shared__ float lSc[8][16];       // softmax-layout -> C-layout relay

    const int tid = threadIdx.x, w = tid >> 6, lane = tid & 63;
    const int bid = blockIdx.x;
    const int idx = bid >> 3;
    const int bh = (bid & 7) * 8 + (idx & 7);    // 8 bh per XCD
    const int bx = idx >> 3;

    const u16* qb = q + (size_t)bh * T_LEN * DK;
    const u16* kb = k + (size_t)bh * T_LEN * DK;
    const u16* vb = v + (size_t)bh * T_LEN * DK;

    const int g = lane >> 4;
    const int ccol = lane & 15;
    const int kg = tid >> 4;
    const int dc = tid & 15;
    const int wk = w - 4;
    const int b_ = bh >> 4, h_ = bh & 15;

    for (int seg = 0; seg < 2; ++seg) {
        const int qblk = seg ? (15 - bx) : bx;
        const int q0 = qblk * 128;
        const int ntiles = 2 * qblk + 2;
        const int rowbase = q0 + w * 16;
        const int myq = rowbase + ccol;

        bf16x8 qa[2];
#pragma unroll
        for (int kk = 0; kk < 2; ++kk)
            qa[kk] = *(const bf16x8*)(qb + (size_t)(rowbase + ccol) * DK + kk * 32 + g * 8);

        f32x4 oacc[4] = {};
        float mrow = -1e30f, lpart = 0.f;

        u16x4 vr[4];
        if (w >= 4) {
#pragma unroll
            for (int r2 = 0; r2 < 2; ++r2) {
                int c = r2 * 256 + wk * 64 + lane;
                int row = c >> 3, ch = c & 7;
                __builtin_amdgcn_global_load_lds(
                    (AS1 const void*)(kb + (size_t)row * DK + (ch ^ (row & 7)) * 8),
                    (AS3 void*)(&lK[0][(r2 * 256 + wk * 64) * 8]), 16, 0, 0);
            }
        } else {
#pragma unroll
            for (int i = 0; i < 4; ++i)
                vr[i] = *(const u16x4*)(vb + (size_t)(kg * 4 + i) * DK + dc * 4);
        }

        for (int kt = 0; kt < ntiles; ++kt) {
            const int bf = kt & 1;
            const int kv0 = kt << 6;
            asm volatile("s_waitcnt vmcnt(0)" ::: "memory");
            if (w < 4) {
#pragma unroll
                for (int j = 0; j < 4; ++j) {
                    int d = dc * 4 + j;
                    u16x4 t4;
                    t4[0] = vr[0][j]; t4[1] = vr[1][j]; t4[2] = vr[2][j]; t4[3] = vr[3][j];
                    *(u16x4*)(&lV[bf][d * 64 +
                        (((kg >> 1) ^ ((d >> 1) & 7)) * 8 + (kg & 1) * 4)]) = t4;
                }
            }
            __syncthreads();

            if (kt + 1 < ntiles) {
                const int kvn = (kt + 1) << 6;
                if (w >= 4) {
#pragma unroll
                    for (int r2 = 0; r2 < 2; ++r2) {
                        int c = r2 * 256 + wk * 64 + lane;
                        int row = c >> 3, ch = c & 7;
                        __builtin_amdgcn_global_load_lds(
                            (AS1 const void*)(kb + (size_t)(kvn + row) * DK + (ch ^ (row & 7)) * 8),
                            (AS3 void*)(&lK[bf ^ 1][(r2 * 256 + wk * 64) * 8]), 16, 0, 0);
                    }
                } else {
#pragma unroll
                    for (int i = 0; i < 4; ++i)
                        vr[i] = *(const u16x4*)(vb + (size_t)(kvn + kg * 4 + i) * DK + dc * 4);
                }
            }

            if (kv0 < rowbase + 16) {
                f32x4 sacc[4] = {};
                __builtin_amdgcn_s_setprio(1);
#pragma unroll
                for (int nt = 0; nt < 4; ++nt)
#pragma unroll
                    for (int kk = 0; kk < 2; ++kk) {
                        bf16x8 kf = *(const bf16x8*)(&lK[bf][(nt * 16 + ccol) * 64 +
                                                     (((kk * 4 + g) ^ (ccol & 7)) * 8)]);
                        sacc[nt] = __builtin_amdgcn_mfma_f32_16x16x32_bf16(
                            kf, qa[kk], sacc[nt], 0, 0, 0);
                    }
                __builtin_amdgcn_s_setprio(0);

                const bool full = (kv0 + 63) <= rowbase;
                float mx = -1e30f;
#pragma unroll
                for (int nt = 0; nt < 4; ++nt)
#pragma unroll
                    for (int r = 0; r < 4; ++r) {
                        float sv = sacc[nt][r];
                        if (!full && (kv0 + nt * 16 + g * 4 + r > myq)) sv = -1e30f;
                        sacc[nt][r] = sv;
                        mx = fmaxf(mx, sv);
                    }
                mx = fmaxf(mx, __shfl_xor(mx, 16));
                mx = fmaxf(mx, __shfl_xor(mx, 32));

                const bool skiprow = (mx <= mrow + 8.f);
                float mnew = skiprow ? mrow : mx;
                float p[4][4];
                float rsl = 0.f;
#pragma unroll
                for (int nt = 0; nt < 4; ++nt)
#pragma unroll
                    for (int r = 0; r < 4; ++r) {
                        float pv = __builtin_amdgcn_exp2f(sacc[nt][r] - mnew);
                        p[nt][r] = pv;
                        rsl += pv;
                    }
                float scal = skiprow ? 1.f : __builtin_amdgcn_exp2f(mrow - mnew);
                lpart = lpart * scal + rsl;
                mrow = mnew;

                if (lane < 16) lSc[w][lane] = scal;
#pragma unroll
                for (int nt = 0; nt < 4; ++nt) {
                    u16x4 t4;
                    t4[0] = f2bf(p[nt][0]); t4[1] = f2bf(p[nt][1]);
                    t4[2] = f2bf(p[nt][2]); t4[3] = f2bf(p[nt][3]);
                    *(u16x4*)(&lP[w][ccol * 72 + nt * 16 + g * 4]) = t4;
                }
                asm volatile("s_waitcnt lgkmcnt(0)" ::: "memory");

                f32x4 scalC = *(const f32x4*)(&lSc[w][g * 4]);
                if (__any(!skiprow)) {
#pragma unroll
                    for (int nt2 = 0; nt2 < 4; ++nt2)
#pragma unroll
                        for (int r = 0; r < 4; ++r) oacc[nt2][r] *= scalC[r];
                }

                bf16x8 pa[2];
#pragma unroll
                for (int kk2 = 0; kk2 < 2; ++kk2)
                    pa[kk2] = *(const bf16x8*)(&lP[w][ccol * 72 + kk2 * 32 + g * 8]);

                const int vsw = (ccol >> 1) & 7;
                __builtin_amdgcn_s_setprio(1);
#pragma unroll
                for (int nt2 = 0; nt2 < 4; ++nt2) {
#pragma unroll
                    for (int kk2 = 0; kk2 < 2; ++kk2) {
                        bf16x8 vf = *(const bf16x8*)(&lV[bf][(nt2 * 16 + ccol) * 64 +
                                                     (((kk2 * 4 + g) ^ vsw) * 8)]);
                        oacc[nt2] = __builtin_amdgcn_mfma_f32_16x16x32_bf16(
                            pa[kk2], vf, oacc[nt2], 0, 0, 0);
                    }
                }
                __builtin_amdgcn_s_setprio(0);
            }
        }
        __syncthreads();

        float rs = lpart;
        rs += __shfl_xor(rs, 16);
        rs += __shfl_xor(rs, 32);
        if (lane < 16) lSc[w][lane] = rs;
        asm volatile("s_waitcnt lgkmcnt(0)" ::: "memory");
        f32x4 rsC = *(const f32x4*)(&lSc[w][g * 4]);
#pragma unroll
        for (int r = 0; r < 4; ++r) {
            float inv = 1.0f / rsC[r];
            int trow = rowbase + g * 4 + r;
#pragma unroll
            for (int nt2 = 0; nt2 < 4; ++nt2) {
                float val = oacc[nt2][r] * inv;
                o[(size_t)(b_ * T_LEN + trow) * D_DIM + h_ * DK + nt2 * 16 + ccol] = f2bf(val);
            }
        }
        __syncthreads();
    }
}

// ---------------- launch ----------------
extern "C" void kernel_launch(void* const* d_in, const int* in_sizes, int n_in,
                              void* d_out, int out_size, void* d_ws, size_t ws_size,
                              hipStream_t stream) {
    const float* x  = (const float*)d_in[0];
    const float* Wq = (const float*)d_in[2];
    const float* Wk = (const float*)d_in[3];
    const float* Wv = (const float*)d_in[4];
    const float* Wo = (const float*)d_in[5];
    const float* bq = (const float*)d_in[6];
    const float* bk = (const float*)d_in[7];
    const float* bv = (const float*)d_in[8];
    const float* bo = (const float*)d_in[9];

    char* ws = (char*)d_ws;
    u16* xb   = (u16*)(ws);                    // 16 MB, reused as attn output
    u16* wqb  = (u16*)(ws + 16777216);         // wq|wk|wv|wo contiguous 2MB each
    u16* wob  = (u16*)(ws + 23068672);
    u16* qws  = (u16*)(ws + 25165824);         // q|k|v contiguous 16MB each
    u16* kws  = (u16*)(ws + 41943040);
    u16* vws  = (u16*)(ws + 58720256);
    u16* attnb = xb;

    cvt_all<<<6144, 256, 0, stream>>>(x, Wq, Wk, Wv, Wo, xb, wqb);

    // fused QKV projection: 256^2 8-phase pipeline (r8)
    gemm_qkv<<<384, 512, 0, stream>>>(xb, wqb, bq, bk, bv, qws);

    attn_fwd<<<512, 512, 0, stream>>>(qws, kws, vws, attnb);

    // final projection: 256x128, 256 blocks = 1 clean round
    gemm_o<<<256, 512, 0, stream>>>(attnb, wob, bo, (float*)d_out);
}